// Round 3
// baseline (134.953 us; speedup 1.0000x reference)
//
#include <hip/hip_runtime.h>

// Problem: B=16, H=256, W=256, D=256
//   loss = mean over (b,h,w) of (rec[b,h,w,idx[b]] - in2d[b,h,w])^2
#define HWB    65536      // H*W
#define DDIM   256
#define NTOT   1048576    // B*H*W
#define NBLK   2048       // 512 elements per block; 32 waves/CU (max occupancy)

// ws layout: [0] unsigned counter (memset to 0 each launch)
//            [16..16+NBLK*4) float partials (written unconditionally)
__global__ __launch_bounds__(256) void pjc_fused_kernel(
    const float* __restrict__ rec,
    const float* __restrict__ in2d,
    const int*   __restrict__ sidx,
    unsigned*    __restrict__ counter,
    float*       __restrict__ partial,
    float*       __restrict__ out)
{
    const int tid  = threadIdx.x;
    const int base = blockIdx.x << 9;          // first flat element (b*HWB + hw)
    const int b    = base >> 16;               // uniform per block
    const int d    = sidx[b];

    const float* __restrict__ recd = rec + d;

    const int i0 = base + tid;
    const int i1 = base + 256 + tid;

    // gathers: 1 KiB lane stride (one cache line per element — intrinsic cost)
    float r0 = recd[(size_t)i0 << 8];
    float r1 = recd[(size_t)i1 << 8];
    // coalesced in2d reads
    float x0 = in2d[i0];
    float x1 = in2d[i1];

    float d0 = r0 - x0;
    float d1 = r1 - x1;
    float acc = d0 * d0 + d1 * d1;

    // wave-64 butterfly reduce
    #pragma unroll
    for (int off = 32; off > 0; off >>= 1)
        acc += __shfl_down(acc, off);

    __shared__ float wsum[4];
    __shared__ int   is_last;
    if ((tid & 63) == 0) wsum[tid >> 6] = acc;
    __syncthreads();

    if (tid == 0) {
        float s = wsum[0] + wsum[1] + wsum[2] + wsum[3];
        // device-scope release store: visible across XCD L2s to the finisher
        __hip_atomic_store(&partial[blockIdx.x], s,
                           __ATOMIC_RELEASE, __HIP_MEMORY_SCOPE_AGENT);
        unsigned old = __hip_atomic_fetch_add(counter, 1u,
                           __ATOMIC_ACQ_REL, __HIP_MEMORY_SCOPE_AGENT);
        is_last = (old == NBLK - 1);
    }
    __syncthreads();

    if (is_last) {
        // this block saw all NBLK partials published (acquire on the counter)
        float t = 0.f;
        #pragma unroll
        for (int i = tid; i < NBLK; i += 256)
            t += __hip_atomic_load(&partial[i],
                                   __ATOMIC_RELAXED, __HIP_MEMORY_SCOPE_AGENT);

        #pragma unroll
        for (int off = 32; off > 0; off >>= 1)
            t += __shfl_down(t, off);

        __shared__ float fsum[4];
        if ((tid & 63) == 0) fsum[tid >> 6] = t;
        __syncthreads();
        if (tid == 0)
            out[0] = (fsum[0] + fsum[1] + fsum[2] + fsum[3]) * (1.0f / (float)NTOT);
    }
}

extern "C" void kernel_launch(void* const* d_in, const int* in_sizes, int n_in,
                              void* d_out, int out_size, void* d_ws, size_t ws_size,
                              hipStream_t stream) {
    const float* rec  = (const float*)d_in[0];   // [16,256,256,256] f32
    const float* in2d = (const float*)d_in[1];   // [16,256,256]     f32
    const int*   sidx = (const int*)d_in[2];     // [16]             int32
    float* out = (float*)d_out;                  // scalar f32

    unsigned* counter = (unsigned*)d_ws;
    float*    partial = (float*)((char*)d_ws + 16);

    // re-zero the completion counter every launch (graph-capture safe;
    // kernel leaves it at NBLK, so this keeps replays deterministic)
    hipMemsetAsync(counter, 0, sizeof(unsigned), stream);

    pjc_fused_kernel<<<NBLK, 256, 0, stream>>>(rec, in2d, sidx, counter, partial, out);
}

// Round 4
// 68.594 us; speedup vs baseline: 1.9674x; 1.9674x over previous
//
#include <hip/hip_runtime.h>

// Problem: B=16, H=256, W=256, D=256
//   loss = mean over (b,h,w) of (rec[b,h,w,idx[b]] - in2d[b,h,w])^2
#define HWB    65536      // H*W
#define DDIM   256
#define NTOT   1048576    // B*H*W
#define NBLK   2048       // 512 elements per block; 32 waves/CU (max occupancy)

// ws layout: [0] float   global sum   (memset to 0 each launch)
//            [1] unsigned counter     (memset to 0 each launch)
// RELAXED atomics only — no acquire/release (those cost L2 wb/inv per block
// on gfx950's non-coherent per-XCD L2s: R3 regressed 5x from that).
__global__ __launch_bounds__(256) void pjc_fused_kernel(
    const float* __restrict__ rec,
    const float* __restrict__ in2d,
    const int*   __restrict__ sidx,
    float*       __restrict__ gsum,     // ws[0]
    unsigned*    __restrict__ counter,  // ws[1]
    float*       __restrict__ out)
{
    const int tid  = threadIdx.x;
    const int base = blockIdx.x << 9;          // first flat element (b*HWB + hw)
    const int b    = base >> 16;               // uniform per block
    const int d    = sidx[b];

    const float* __restrict__ recd = rec + d;

    const int i0 = base + tid;
    const int i1 = base + 256 + tid;

    // gathers: 1 KiB lane stride (one cache line per element — intrinsic cost)
    float r0 = recd[(size_t)i0 << 8];
    float r1 = recd[(size_t)i1 << 8];
    // coalesced in2d reads
    float x0 = in2d[i0];
    float x1 = in2d[i1];

    float d0 = r0 - x0;
    float d1 = r1 - x1;
    float acc = d0 * d0 + d1 * d1;

    // wave-64 butterfly reduce
    #pragma unroll
    for (int off = 32; off > 0; off >>= 1)
        acc += __shfl_down(acc, off);

    __shared__ float wsum[4];
    if ((tid & 63) == 0) wsum[tid >> 6] = acc;
    __syncthreads();

    if (tid == 0) {
        float s = wsum[0] + wsum[1] + wsum[2] + wsum[3];
        // returning relaxed atomic: old-value arrival proves the RMW executed
        // at the coherent point. Keep it live so the wait isn't elided.
        float old = atomicAdd(gsum, s);
        asm volatile("" :: "v"(old));          // dependency fence (no codegen)
        unsigned o = atomicAdd(counter, 1u);   // relaxed RMW, serializes at TCC
        if (o == NBLK - 1) {
            // all 2047 prior counter RMWs done => all gsum RMWs done.
            // atomic read-at-coherent-point (immune to stale L1/L2):
            float tot = atomicAdd(gsum, 0.0f);
            out[0] = tot * (1.0f / (float)NTOT);
        }
    }
}

extern "C" void kernel_launch(void* const* d_in, const int* in_sizes, int n_in,
                              void* d_out, int out_size, void* d_ws, size_t ws_size,
                              hipStream_t stream) {
    const float* rec  = (const float*)d_in[0];   // [16,256,256,256] f32
    const float* in2d = (const float*)d_in[1];   // [16,256,256]     f32
    const int*   sidx = (const int*)d_in[2];     // [16]             int32
    float* out = (float*)d_out;                  // scalar f32

    float*    gsum    = (float*)d_ws;
    unsigned* counter = (unsigned*)((char*)d_ws + 4);

    // re-zero sum+counter every launch (8 B, graph-capture safe)
    hipMemsetAsync(d_ws, 0, 8, stream);

    pjc_fused_kernel<<<NBLK, 256, 0, stream>>>(rec, in2d, sidx, gsum, counter, out);
}

// Round 5
// 26.404 us; speedup vs baseline: 5.1110x; 2.5978x over previous
//
#include <hip/hip_runtime.h>

// Problem: B=16, H=256, W=256, D=256
//   loss = mean over (b,h,w) of (rec[b,h,w,idx[b]] - in2d[b,h,w])^2
#define HWB    65536      // H*W
#define DDIM   256
#define NTOT   1048576    // B*H*W
#define NBLK   1024       // 512 threads/block, 1024 elems/block; 32 waves/CU

// Lessons burned in:
//  - R3: agent-scope acq/rel atomics => per-block L2 wb/inv, 5x regression.
//  - R4: even relaxed same-line returning RMWs x2048 blocks => ~40us tail.
//  => two clean kernels, partials via plain stores, no atomics at all.
__global__ __launch_bounds__(512) void pjc_main_kernel(
    const float* __restrict__ rec,
    const float* __restrict__ in2d,
    const int*   __restrict__ sidx,
    float*       __restrict__ partial)
{
    const int tid  = threadIdx.x;
    const int base = blockIdx.x << 10;         // 1024 consecutive flat elements
    const int b    = base >> 16;               // uniform per block (1024 | 65536)
    const int d    = sidx[b];

    const float* __restrict__ recd = rec + d;

    const int i0 = base + tid;
    const int i1 = base + 512 + tid;

    // gathers: 1 KiB lane stride, one 128B line per element (intrinsic cost).
    // non-temporal: every line is single-use -> evict-first, keep L2 clean.
    float r0 = __builtin_nontemporal_load(&recd[(size_t)i0 << 8]);
    float r1 = __builtin_nontemporal_load(&recd[(size_t)i1 << 8]);
    // coalesced in2d reads
    float x0 = in2d[i0];
    float x1 = in2d[i1];

    float d0 = r0 - x0;
    float d1 = r1 - x1;
    float acc = d0 * d0 + d1 * d1;

    // wave-64 butterfly reduce
    #pragma unroll
    for (int off = 32; off > 0; off >>= 1)
        acc += __shfl_down(acc, off);

    __shared__ float wsum[8];
    if ((tid & 63) == 0) wsum[tid >> 6] = acc;
    __syncthreads();

    if (tid == 0) {
        float s = 0.f;
        #pragma unroll
        for (int i = 0; i < 8; ++i) s += wsum[i];
        partial[blockIdx.x] = s;
    }
}

// Reduce NBLK partials -> scalar mean. One block, 256 threads, float4 reads.
__global__ __launch_bounds__(256) void pjc_final_kernel(
    const float* __restrict__ partial,
    float*       __restrict__ out)
{
    const int tid = threadIdx.x;
    const float4 p = reinterpret_cast<const float4*>(partial)[tid];  // 256*4 = 1024
    float s = (p.x + p.y) + (p.z + p.w);

    #pragma unroll
    for (int off = 32; off > 0; off >>= 1)
        s += __shfl_down(s, off);

    __shared__ float wsum[4];
    if ((tid & 63) == 0) wsum[tid >> 6] = s;
    __syncthreads();

    if (tid == 0)
        out[0] = (wsum[0] + wsum[1] + wsum[2] + wsum[3]) * (1.0f / (float)NTOT);
}

extern "C" void kernel_launch(void* const* d_in, const int* in_sizes, int n_in,
                              void* d_out, int out_size, void* d_ws, size_t ws_size,
                              hipStream_t stream) {
    const float* rec  = (const float*)d_in[0];   // [16,256,256,256] f32
    const float* in2d = (const float*)d_in[1];   // [16,256,256]     f32
    const int*   sidx = (const int*)d_in[2];     // [16]             int32
    float* out = (float*)d_out;                  // scalar f32
    float* ws  = (float*)d_ws;                   // >= NBLK floats (4 KiB)

    pjc_main_kernel<<<NBLK, 512, 0, stream>>>(rec, in2d, sidx, ws);
    pjc_final_kernel<<<1, 256, 0, stream>>>(ws, out);
}